// Round 1
// baseline (5997.413 us; speedup 1.0000x reference)
//
#include <hip/hip_runtime.h>
#include <hip/hip_bf16.h>
#include <math.h>

// ---------------------------------------------------------------------------
// fp32 SIMT tiled GEMM: C[M,Nc] = A[M,K] @ B[K,Nc](col offset bcol) [+bias][+gelu]
// EPI: 0 = none, 1 = +bias, 2 = +bias +exact gelu
// ---------------------------------------------------------------------------
#define TS 64
#define KS 16

template<int EPI>
__global__ __launch_bounds__(256) void gemm_f32(
    const float* __restrict__ A, const float* __restrict__ B,
    const float* __restrict__ bias, float* __restrict__ C,
    int M, int Nc, int K, int lda, int ldb, int ldc, int bcol)
{
    __shared__ float As[KS][TS + 4];   // +4 pad: 16B-aligned rows, no 16-way conflicts
    __shared__ float Bs[KS][TS + 4];
    const int tid = threadIdx.x;
    const int tx = tid & 15, ty = tid >> 4;
    const int bm = blockIdx.y * TS, bn = blockIdx.x * TS;

    float acc[4][4] = {};

    for (int k0 = 0; k0 < K; k0 += KS) {
        #pragma unroll
        for (int i = 0; i < 4; ++i) {               // A tile 64x16 (1024 elems)
            int idx = tid + i * 256;
            int m = idx >> 4, kk = idx & 15;
            As[kk][m] = A[(size_t)(bm + m) * lda + k0 + kk];
        }
        #pragma unroll
        for (int i = 0; i < 4; ++i) {               // B tile 16x64, coalesced
            int idx = tid + i * 256;
            int kk = idx >> 6, n = idx & 63;
            Bs[kk][n] = B[(size_t)(k0 + kk) * ldb + bcol + bn + n];
        }
        __syncthreads();
        #pragma unroll
        for (int kk = 0; kk < KS; ++kk) {
            float a[4], b4[4];
            #pragma unroll
            for (int i = 0; i < 4; ++i) a[i]  = As[kk][ty * 4 + i];
            #pragma unroll
            for (int j = 0; j < 4; ++j) b4[j] = Bs[kk][tx * 4 + j];
            #pragma unroll
            for (int i = 0; i < 4; ++i)
                #pragma unroll
                for (int j = 0; j < 4; ++j)
                    acc[i][j] = fmaf(a[i], b4[j], acc[i][j]);
        }
        __syncthreads();
    }

    #pragma unroll
    for (int i = 0; i < 4; ++i) {
        int row = bm + ty * 4 + i;
        #pragma unroll
        for (int j = 0; j < 4; ++j) {
            int col = bn + tx * 4 + j;
            float v = acc[i][j];
            if (EPI >= 1) v += bias[col];
            if (EPI == 2) v = 0.5f * v * (1.0f + erff(v * 0.7071067811865475f));
            C[(size_t)row * ldc + col] = v;
        }
    }
}

// ---------------------------------------------------------------------------
// drofe: in-place RoPE-like rotation on Q and K, layout (B*N, C) col = h*64+d
// pair index within head i = (d/2) in [0,32): i<16 -> fb0*freqs[i], else fb1*freqs[i-16]
// ---------------------------------------------------------------------------
__global__ __launch_bounds__(256) void drofe_kernel(
    float* __restrict__ Qm, float* __restrict__ Km,
    const float* __restrict__ freqband, const float* __restrict__ demo,
    int B, int N, int C)
{
    const float PI_F = 3.14159265358979323846f;
    const int halfC = C / 2;                         // 512
    int total = B * N * halfC;
    for (int idx = blockIdx.x * blockDim.x + threadIdx.x; idx < total;
         idx += gridDim.x * blockDim.x) {
        int col2 = idx % halfC;
        int row  = idx / halfC;                      // b*N + n
        int n = row % N, b = row / N;
        int i  = col2 & 31;                          // pair index within head (D/2=32)
        int ii = (i < 16) ? i : i - 16;
        float fb = (i < 16) ? freqband[n * 2 + 0] : freqband[n * 2 + 1];
        float freq = (1.0f + (float)ii * (4.0f / 15.0f)) * PI_F;  // linspace(1,5,16)*pi
        float ang = fb * freq;
        float cv = cosf(ang), sv = sinf(ang);
        float ca = cv * demo[b * 2 + 0];             // cos*age
        float sg = sv * demo[b * 2 + 1];             // sin*gender
        float2* q2 = reinterpret_cast<float2*>(Qm);
        float2* k2 = reinterpret_cast<float2*>(Km);
        size_t p = (size_t)row * halfC + col2;
        float2 q = q2[p];
        float2 k = k2[p];
        // out[2i] = e*ca - o*sg ; out[2i+1] = o*ca + e*sg
        q2[p] = make_float2(q.x * ca - q.y * sg, q.y * ca + q.x * sg);
        k2[p] = make_float2(k.x * ca - k.y * sg, k.y * ca + k.x * sg);
    }
}

// ---------------------------------------------------------------------------
// Flash-style attention, fp32. Layouts: Q/K/V/O all (B*N, C) with col = h*64+d.
// Block = 256 thr = 4 waves; block handles 16 q-rows of one (b,h); each wave 4 rows.
// K/V staged in LDS 64-key tiles; stride 65 -> <=2-way bank conflicts (free).
// ---------------------------------------------------------------------------
#define AT_ROWS 16
__global__ __launch_bounds__(256) void attn_kernel(
    const float* __restrict__ Q, const float* __restrict__ K,
    const float* __restrict__ V, float* __restrict__ O,
    int B, int H, int N, int C)
{
    __shared__ float Ks[64][65];
    __shared__ float Vs[64][65];
    __shared__ float Qs[AT_ROWS][65];
    const int ntiles = N / AT_ROWS;                  // 64
    const int bh = blockIdx.x / ntiles;
    const int n0 = (blockIdx.x % ntiles) * AT_ROWS;
    const int b = bh / H, h = bh % H;
    const int tid = threadIdx.x;
    const int w = tid >> 6, lane = tid & 63;
    const float scale = 0.125f;                      // D^-0.5, D=64

    for (int i = tid; i < AT_ROWS * 64; i += 256) {
        int r = i >> 6, d = i & 63;
        Qs[r][d] = Q[(size_t)(b * N + n0 + r) * C + h * 64 + d];
    }

    float m[4], l[4], acc[4];
    #pragma unroll
    for (int i = 0; i < 4; ++i) { m[i] = -INFINITY; l[i] = 0.f; acc[i] = 0.f; }
    __syncthreads();

    for (int t = 0; t < N; t += 64) {
        for (int i = tid; i < 64 * 64; i += 256) {
            int kk = i >> 6, d = i & 63;
            size_t g = (size_t)(b * N + t + kk) * C + h * 64 + d;
            Ks[kk][d] = K[g];
            Vs[kk][d] = V[g];
        }
        __syncthreads();
        #pragma unroll
        for (int i = 0; i < 4; ++i) {
            int r = w * 4 + i;
            float s = 0.f;
            #pragma unroll
            for (int d = 0; d < 64; ++d) s = fmaf(Qs[r][d], Ks[lane][d], s);
            s *= scale;
            float tm = s;
            #pragma unroll
            for (int msk = 1; msk < 64; msk <<= 1) tm = fmaxf(tm, __shfl_xor(tm, msk));
            float mn = fmaxf(m[i], tm);
            float corr = __expf(m[i] - mn);          // first tile: exp(-inf)=0
            float p = __expf(s - mn);
            float ps = p;
            #pragma unroll
            for (int msk = 1; msk < 64; msk <<= 1) ps += __shfl_xor(ps, msk);
            l[i] = l[i] * corr + ps;
            acc[i] *= corr;
            #pragma unroll
            for (int kk2 = 0; kk2 < 64; ++kk2)
                acc[i] = fmaf(__shfl(p, kk2), Vs[kk2][lane], acc[i]);
        }
        __syncthreads();
    }

    #pragma unroll
    for (int i = 0; i < 4; ++i) {
        int n = n0 + w * 4 + i;
        O[(size_t)(b * N + n) * C + h * 64 + lane] = acc[i] / l[i];
    }
}

// ---------------------------------------------------------------------------
// Fused residual + LayerNorm per row: out = LN(x + gamma*y) * w + b
// ---------------------------------------------------------------------------
__global__ __launch_bounds__(256) void ln_res_kernel(
    const float* __restrict__ x, const float* __restrict__ y,
    const float* __restrict__ gamma, const float* __restrict__ w,
    const float* __restrict__ bia, float* __restrict__ out, int C)
{
    const int row = blockIdx.x;
    __shared__ float buf[1024];
    __shared__ float red[8];
    const size_t base = (size_t)row * C;
    float s = 0.f, ss = 0.f;
    for (int c = threadIdx.x; c < C; c += 256) {
        float v = x[base + c] + gamma[c] * y[base + c];
        buf[c] = v; s += v; ss += v * v;
    }
    #pragma unroll
    for (int msk = 1; msk < 64; msk <<= 1) { s += __shfl_xor(s, msk); ss += __shfl_xor(ss, msk); }
    int wv = threadIdx.x >> 6, lane = threadIdx.x & 63;
    if (lane == 0) { red[wv * 2] = s; red[wv * 2 + 1] = ss; }
    __syncthreads();
    if (threadIdx.x == 0) {
        float S = 0.f, SS = 0.f;
        #pragma unroll
        for (int i = 0; i < 4; ++i) { S += red[2 * i]; SS += red[2 * i + 1]; }
        red[0] = S; red[1] = SS;
    }
    __syncthreads();
    float mu = red[0] / C;
    float var = red[1] / C - mu * mu;
    float rstd = rsqrtf(var + 1e-5f);
    for (int c = threadIdx.x; c < C; c += 256)
        out[base + c] = (buf[c] - mu) * rstd * w[c] + bia[c];
}

// ---------------------------------------------------------------------------
extern "C" void kernel_launch(void* const* d_in, const int* in_sizes, int n_in,
                              void* d_out, int out_size, void* d_ws, size_t ws_size,
                              hipStream_t stream)
{
    const float* x      = (const float*)d_in[0];
    const float* demo   = (const float*)d_in[1];
    const float* expl   = (const float*)d_in[2];
    const float* fb     = (const float*)d_in[3];
    const float* w_qkv  = (const float*)d_in[4];
    const float* w_proj = (const float*)d_in[5];
    const float* b_proj = (const float*)d_in[6];
    const float* gamma1 = (const float*)d_in[7];
    const float* gamma2 = (const float*)d_in[8];
    const float* ln1_w  = (const float*)d_in[9];
    const float* ln1_b  = (const float*)d_in[10];
    const float* ln2_w  = (const float*)d_in[11];
    const float* ln2_b  = (const float*)d_in[12];
    const float* w1     = (const float*)d_in[13];
    const float* b1     = (const float*)d_in[14];
    const float* w2     = (const float*)d_in[15];
    const float* b2     = (const float*)d_in[16];
    float* out = (float*)d_out;

    const int B = 8, N = 1024, C = 1024, F = 4096, H = 16;
    const int M = B * N;                       // 8192
    const size_t SZ = (size_t)M * C;           // 8388608 floats

    // workspace layout (floats): total 8*SZ = 268.4 MB
    float* ws  = (float*)d_ws;
    float* Qb  = ws + 0 * SZ;
    float* Kb  = ws + 1 * SZ;
    float* Vb  = ws + 2 * SZ;
    float* Ob  = ws + 3 * SZ;
    float* Hid = ws + 4 * SZ;                  // 4*SZ floats (M x F)
    float* Pb  = Qb;                           // reuse: proj out
    float* X1  = Kb;                           // reuse: post-LN1
    float* H2  = Vb;                           // reuse: MLP out

    dim3 blk(256);
    dim3 g1(C / TS, M / TS);
    // QKV projections (Q,K from explanation; V from x)
    hipLaunchKernelGGL((gemm_f32<0>), g1, blk, 0, stream, expl, w_qkv, (const float*)nullptr, Qb, M, C, C, C, 3 * C, C, 0);
    hipLaunchKernelGGL((gemm_f32<0>), g1, blk, 0, stream, expl, w_qkv, (const float*)nullptr, Kb, M, C, C, C, 3 * C, C, C);
    hipLaunchKernelGGL((gemm_f32<0>), g1, blk, 0, stream, x,    w_qkv, (const float*)nullptr, Vb, M, C, C, C, 3 * C, C, 2 * C);
    // drofe on Q,K (in place)
    int pairs = B * N * (C / 2);
    hipLaunchKernelGGL(drofe_kernel, dim3(pairs / 256), blk, 0, stream, Qb, Kb, fb, demo, B, N, C);
    // attention
    hipLaunchKernelGGL(attn_kernel, dim3(B * H * (N / AT_ROWS)), blk, 0, stream, Qb, Kb, Vb, Ob, B, H, N, C);
    // output projection (+bias)
    hipLaunchKernelGGL((gemm_f32<1>), g1, blk, 0, stream, Ob, w_proj, b_proj, Pb, M, C, C, C, C, C, 0);
    // residual + LN1
    hipLaunchKernelGGL(ln_res_kernel, dim3(M), blk, 0, stream, x, Pb, gamma1, ln1_w, ln1_b, X1, C);
    // MLP
    dim3 g2(F / TS, M / TS);
    hipLaunchKernelGGL((gemm_f32<2>), g2, blk, 0, stream, X1, w1, b1, Hid, M, F, C, C, F, F, 0);
    hipLaunchKernelGGL((gemm_f32<1>), g1, blk, 0, stream, Hid, w2, b2, H2, M, C, F, F, C, C, 0);
    // residual + LN2 -> out
    hipLaunchKernelGGL(ln_res_kernel, dim3(M), blk, 0, stream, X1, H2, gamma2, ln2_w, ln2_b, out, C);
}

// Round 2
// 3092.681 us; speedup vs baseline: 1.9392x; 1.9392x over previous
//
#include <hip/hip_runtime.h>
#include <hip/hip_bf16.h>
#include <math.h>

typedef __attribute__((ext_vector_type(8))) short bf16x8;
typedef __attribute__((ext_vector_type(4))) float f32x4;

__device__ inline unsigned short f2bf(float f) {
    union { float f; unsigned u; } v; v.f = f;
    unsigned r = (v.u + 0x7fff + ((v.u >> 16) & 1)) >> 16;   // RNE
    return (unsigned short)r;
}

// ---------------------------------------------------------------------------
// fp32 SIMT tiled GEMM: C[M,Nc] = A[M,K] @ B[K,Nc](col offset bcol) [+bias][+gelu]
// EPI: 0 = none, 1 = +bias, 2 = +bias +exact gelu
// ---------------------------------------------------------------------------
#define TS 64
#define KS 16

template<int EPI>
__global__ __launch_bounds__(256) void gemm_f32(
    const float* __restrict__ A, const float* __restrict__ B,
    const float* __restrict__ bias, float* __restrict__ C,
    int M, int Nc, int K, int lda, int ldb, int ldc, int bcol)
{
    __shared__ float As[KS][TS + 4];
    __shared__ float Bs[KS][TS + 4];
    const int tid = threadIdx.x;
    const int tx = tid & 15, ty = tid >> 4;
    const int bm = blockIdx.y * TS, bn = blockIdx.x * TS;

    float acc[4][4] = {};

    for (int k0 = 0; k0 < K; k0 += KS) {
        #pragma unroll
        for (int i = 0; i < 4; ++i) {
            int idx = tid + i * 256;
            int m = idx >> 4, kk = idx & 15;
            As[kk][m] = A[(size_t)(bm + m) * lda + k0 + kk];
        }
        #pragma unroll
        for (int i = 0; i < 4; ++i) {
            int idx = tid + i * 256;
            int kk = idx >> 6, n = idx & 63;
            Bs[kk][n] = B[(size_t)(k0 + kk) * ldb + bcol + bn + n];
        }
        __syncthreads();
        #pragma unroll
        for (int kk = 0; kk < KS; ++kk) {
            float a[4], b4[4];
            #pragma unroll
            for (int i = 0; i < 4; ++i) a[i]  = As[kk][ty * 4 + i];
            #pragma unroll
            for (int j = 0; j < 4; ++j) b4[j] = Bs[kk][tx * 4 + j];
            #pragma unroll
            for (int i = 0; i < 4; ++i)
                #pragma unroll
                for (int j = 0; j < 4; ++j)
                    acc[i][j] = fmaf(a[i], b4[j], acc[i][j]);
        }
        __syncthreads();
    }

    #pragma unroll
    for (int i = 0; i < 4; ++i) {
        int row = bm + ty * 4 + i;
        #pragma unroll
        for (int j = 0; j < 4; ++j) {
            int col = bn + tx * 4 + j;
            float v = acc[i][j];
            if (EPI >= 1) v += bias[col];
            if (EPI == 2) v = 0.5f * v * (1.0f + erff(v * 0.7071067811865475f));
            C[(size_t)row * ldc + col] = v;
        }
    }
}

// ---------------------------------------------------------------------------
// drofe: in-place RoPE-like rotation on Q and K, layout (B*N, C) col = h*64+d
// ---------------------------------------------------------------------------
__global__ __launch_bounds__(256) void drofe_kernel(
    float* __restrict__ Qm, float* __restrict__ Km,
    const float* __restrict__ freqband, const float* __restrict__ demo,
    int B, int N, int C)
{
    const float PI_F = 3.14159265358979323846f;
    const int halfC = C / 2;
    int total = B * N * halfC;
    for (int idx = blockIdx.x * blockDim.x + threadIdx.x; idx < total;
         idx += gridDim.x * blockDim.x) {
        int col2 = idx % halfC;
        int row  = idx / halfC;
        int n = row % N, b = row / N;
        int i  = col2 & 31;
        int ii = (i < 16) ? i : i - 16;
        float fb = (i < 16) ? freqband[n * 2 + 0] : freqband[n * 2 + 1];
        float freq = (1.0f + (float)ii * (4.0f / 15.0f)) * PI_F;
        float ang = fb * freq;
        float cv = cosf(ang), sv = sinf(ang);
        float ca = cv * demo[b * 2 + 0];
        float sg = sv * demo[b * 2 + 1];
        float2* q2 = reinterpret_cast<float2*>(Qm);
        float2* k2 = reinterpret_cast<float2*>(Km);
        size_t p = (size_t)row * halfC + col2;
        float2 q = q2[p];
        float2 k = k2[p];
        q2[p] = make_float2(q.x * ca - q.y * sg, q.y * ca + q.x * sg);
        k2[p] = make_float2(k.x * ca - k.y * sg, k.y * ca + k.x * sg);
    }
}

// ---------------------------------------------------------------------------
// Flash attention, bf16 MFMA (16x16x32), fp32 accum.
// Block = 256 thr (4 waves); block owns one (b,h) and 64 q-rows (16/wave).
// KV tiles of 64 keys staged in LDS bf16; K row-major [64][72], V transposed
// [d][k] [64][72]; per-wave P buffer [16][72]. 144B row stride => b128 frag
// reads land 8 lanes per bank-quad = conflict-free.
// MFMA layouts (gfx950, verified m89/m91): A row=l&15, k=(l>>4)*8+j;
// B col=l&15, k=(l>>4)*8+j; C col=l&15, row=(l>>4)*4+r.
// ---------------------------------------------------------------------------
#define LDK 72

__global__ __launch_bounds__(256) void attn_mfma(
    const float* __restrict__ Q, const float* __restrict__ K,
    const float* __restrict__ V, float* __restrict__ O,
    int B, int H, int N, int C)
{
    __shared__ unsigned short Ks[64 * LDK];
    __shared__ unsigned short Vt[64 * LDK];
    __shared__ unsigned short Ps[4][16 * LDK];

    const int nqb = N / 64;                       // 16
    const int bh = blockIdx.x / nqb;
    const int q0 = (blockIdx.x % nqb) * 64;
    const int b = bh / H, h = bh % H;
    const int tid = threadIdx.x;
    const int w = tid >> 6, lane = tid & 63;
    const int lg = lane >> 4, lk = lane & 15;
    const float scale = 0.125f;                   // D^-0.5 folded into Q

    // Q A-fragments for this wave's 16 rows: row=lk, k=kh*32+lg*8+j
    bf16x8 qf[2];
    {
        const float* qrow = Q + (size_t)(b * N + q0 + w * 16 + lk) * C + h * 64;
        #pragma unroll
        for (int kh = 0; kh < 2; ++kh)
            #pragma unroll
            for (int j = 0; j < 8; ++j)
                qf[kh][j] = (short)f2bf(qrow[kh * 32 + lg * 8 + j] * scale);
    }

    f32x4 o[4] = {};                              // d-subtiles, C-layout
    float mrow[4], lrow[4];
    #pragma unroll
    for (int r = 0; r < 4; ++r) { mrow[r] = -INFINITY; lrow[r] = 0.f; }

    for (int t0 = 0; t0 < N; t0 += 64) {
        for (int i = tid; i < 64 * 64; i += 256) {
            int k = i >> 6, d = i & 63;
            size_t g = (size_t)(b * N + t0 + k) * C + h * 64 + d;
            Ks[k * LDK + d] = f2bf(K[g]);
            Vt[d * LDK + k] = f2bf(V[g]);
        }
        __syncthreads();

        // S = Q·K^T  (4 key-subtiles of 16)
        f32x4 s[4];
        #pragma unroll
        for (int sub = 0; sub < 4; ++sub) {
            f32x4 acc = {0.f, 0.f, 0.f, 0.f};
            #pragma unroll
            for (int kh = 0; kh < 2; ++kh) {
                bf16x8 kf = *(const bf16x8*)(&Ks[(sub * 16 + lk) * LDK + kh * 32 + lg * 8]);
                acc = __builtin_amdgcn_mfma_f32_16x16x32_bf16(qf[kh], kf, acc, 0, 0, 0);
            }
            s[sub] = acc;
        }

        // online softmax; q = lg*4 + r, key = sub*16 + lk
        #pragma unroll
        for (int r = 0; r < 4; ++r) {
            float tm = fmaxf(fmaxf(s[0][r], s[1][r]), fmaxf(s[2][r], s[3][r]));
            #pragma unroll
            for (int msk = 1; msk < 16; msk <<= 1) tm = fmaxf(tm, __shfl_xor(tm, msk));
            float mn = fmaxf(mrow[r], tm);
            float corr = __expf(mrow[r] - mn);
            mrow[r] = mn;
            float psum = 0.f;
            unsigned short pb[4];
            #pragma unroll
            for (int sub = 0; sub < 4; ++sub) {
                float p = __expf(s[sub][r] - mn);
                psum += p;
                pb[sub] = f2bf(p);
            }
            #pragma unroll
            for (int msk = 1; msk < 16; msk <<= 1) psum += __shfl_xor(psum, msk);
            lrow[r] = lrow[r] * corr + psum;
            #pragma unroll
            for (int ds = 0; ds < 4; ++ds) o[ds][r] *= corr;
            int q = lg * 4 + r;
            #pragma unroll
            for (int sub = 0; sub < 4; ++sub)
                Ps[w][q * LDK + sub * 16 + lk] = pb[sub];
        }
        asm volatile("s_waitcnt lgkmcnt(0)" ::: "memory");  // per-wave P RAW

        // O += P·V : A=P (row=lk=q, k=key), B=V^T-staged (col=lk=d-local)
        #pragma unroll
        for (int kh = 0; kh < 2; ++kh) {
            bf16x8 pf = *(const bf16x8*)(&Ps[w][lk * LDK + kh * 32 + lg * 8]);
            #pragma unroll
            for (int ds = 0; ds < 4; ++ds) {
                bf16x8 vf = *(const bf16x8*)(&Vt[(ds * 16 + lk) * LDK + kh * 32 + lg * 8]);
                o[ds] = __builtin_amdgcn_mfma_f32_16x16x32_bf16(pf, vf, o[ds], 0, 0, 0);
            }
        }
        __syncthreads();
    }

    #pragma unroll
    for (int ds = 0; ds < 4; ++ds)
        #pragma unroll
        for (int r = 0; r < 4; ++r) {
            int q = lg * 4 + r;
            O[(size_t)(b * N + q0 + w * 16 + q) * C + h * 64 + ds * 16 + lk] =
                o[ds][r] / lrow[r];
        }
}

// ---------------------------------------------------------------------------
// Fused residual + LayerNorm per row: out = LN(x + gamma*y) * w + b
// ---------------------------------------------------------------------------
__global__ __launch_bounds__(256) void ln_res_kernel(
    const float* __restrict__ x, const float* __restrict__ y,
    const float* __restrict__ gamma, const float* __restrict__ w,
    const float* __restrict__ bia, float* __restrict__ out, int C)
{
    const int row = blockIdx.x;
    __shared__ float buf[1024];
    __shared__ float red[8];
    const size_t base = (size_t)row * C;
    float s = 0.f, ss = 0.f;
    for (int c = threadIdx.x; c < C; c += 256) {
        float v = x[base + c] + gamma[c] * y[base + c];
        buf[c] = v; s += v; ss += v * v;
    }
    #pragma unroll
    for (int msk = 1; msk < 64; msk <<= 1) { s += __shfl_xor(s, msk); ss += __shfl_xor(ss, msk); }
    int wv = threadIdx.x >> 6, lane = threadIdx.x & 63;
    if (lane == 0) { red[wv * 2] = s; red[wv * 2 + 1] = ss; }
    __syncthreads();
    if (threadIdx.x == 0) {
        float S = 0.f, SS = 0.f;
        #pragma unroll
        for (int i = 0; i < 4; ++i) { S += red[2 * i]; SS += red[2 * i + 1]; }
        red[0] = S; red[1] = SS;
    }
    __syncthreads();
    float mu = red[0] / C;
    float var = red[1] / C - mu * mu;
    float rstd = rsqrtf(var + 1e-5f);
    for (int c = threadIdx.x; c < C; c += 256)
        out[base + c] = (buf[c] - mu) * rstd * w[c] + bia[c];
}

// ---------------------------------------------------------------------------
extern "C" void kernel_launch(void* const* d_in, const int* in_sizes, int n_in,
                              void* d_out, int out_size, void* d_ws, size_t ws_size,
                              hipStream_t stream)
{
    const float* x      = (const float*)d_in[0];
    const float* demo   = (const float*)d_in[1];
    const float* expl   = (const float*)d_in[2];
    const float* fb     = (const float*)d_in[3];
    const float* w_qkv  = (const float*)d_in[4];
    const float* w_proj = (const float*)d_in[5];
    const float* b_proj = (const float*)d_in[6];
    const float* gamma1 = (const float*)d_in[7];
    const float* gamma2 = (const float*)d_in[8];
    const float* ln1_w  = (const float*)d_in[9];
    const float* ln1_b  = (const float*)d_in[10];
    const float* ln2_w  = (const float*)d_in[11];
    const float* ln2_b  = (const float*)d_in[12];
    const float* w1     = (const float*)d_in[13];
    const float* b1     = (const float*)d_in[14];
    const float* w2     = (const float*)d_in[15];
    const float* b2     = (const float*)d_in[16];
    float* out = (float*)d_out;

    const int B = 8, N = 1024, C = 1024, F = 4096, H = 16;
    const int M = B * N;
    const size_t SZ = (size_t)M * C;

    float* ws  = (float*)d_ws;
    float* Qb  = ws + 0 * SZ;
    float* Kb  = ws + 1 * SZ;
    float* Vb  = ws + 2 * SZ;
    float* Ob  = ws + 3 * SZ;
    float* Hid = ws + 4 * SZ;                  // M x F
    float* Pb  = Qb;
    float* X1  = Kb;
    float* H2  = Vb;

    dim3 blk(256);
    dim3 g1(C / TS, M / TS);
    hipLaunchKernelGGL((gemm_f32<0>), g1, blk, 0, stream, expl, w_qkv, (const float*)nullptr, Qb, M, C, C, C, 3 * C, C, 0);
    hipLaunchKernelGGL((gemm_f32<0>), g1, blk, 0, stream, expl, w_qkv, (const float*)nullptr, Kb, M, C, C, C, 3 * C, C, C);
    hipLaunchKernelGGL((gemm_f32<0>), g1, blk, 0, stream, x,    w_qkv, (const float*)nullptr, Vb, M, C, C, C, 3 * C, C, 2 * C);
    int pairs = B * N * (C / 2);
    hipLaunchKernelGGL(drofe_kernel, dim3(pairs / 256), blk, 0, stream, Qb, Kb, fb, demo, B, N, C);
    hipLaunchKernelGGL(attn_mfma, dim3(B * H * (N / 64)), blk, 0, stream, Qb, Kb, Vb, Ob, B, H, N, C);
    hipLaunchKernelGGL((gemm_f32<1>), g1, blk, 0, stream, Ob, w_proj, b_proj, Pb, M, C, C, C, C, C, 0);
    hipLaunchKernelGGL(ln_res_kernel, dim3(M), blk, 0, stream, x, Pb, gamma1, ln1_w, ln1_b, X1, C);
    dim3 g2(F / TS, M / TS);
    hipLaunchKernelGGL((gemm_f32<2>), g2, blk, 0, stream, X1, w1, b1, Hid, M, F, C, C, F, F, 0);
    hipLaunchKernelGGL((gemm_f32<1>), g1, blk, 0, stream, Hid, w2, b2, H2, M, C, F, F, C, C, 0);
    hipLaunchKernelGGL(ln_res_kernel, dim3(M), blk, 0, stream, X1, H2, gamma2, ln2_w, ln2_b, out, C);
}

// Round 3
// 633.343 us; speedup vs baseline: 9.4694x; 4.8831x over previous
//
#include <hip/hip_runtime.h>
#include <hip/hip_bf16.h>
#include <math.h>

typedef __attribute__((ext_vector_type(8))) short bf16x8;
typedef __attribute__((ext_vector_type(4))) float f32x4;
typedef __attribute__((ext_vector_type(4))) unsigned short u16x4;

__device__ inline unsigned short f2bf(float f) {
    union { float f; unsigned u; } v; v.f = f;
    unsigned r = (v.u + 0x7fff + ((v.u >> 16) & 1)) >> 16;   // RNE
    return (unsigned short)r;
}

#define GLL16(gp, lp) __builtin_amdgcn_global_load_lds(                      \
    (const __attribute__((address_space(1))) void*)(gp),                     \
    (__attribute__((address_space(3))) void*)(lp), 16, 0, 0)

// ---------------------------------------------------------------------------
// bf16 MFMA GEMM, m97 structure: 128x128 tile, BK=32, 4 waves (2x2), each wave
// 64x64 = 4x4 frags of 16x16x32. A [M][K] bf16, Bt [N][K] bf16 (B transposed),
// both staged k-contiguous in LDS via global_load_lds width=16.
// EPI: 0=none 1=+bias 2=+bias+gelu(exact). OUT_BF: write bf16 instead of f32.
// ---------------------------------------------------------------------------
template<int EPI, int OUT_BF>
__global__ __launch_bounds__(256) void gemm_bf(
    const unsigned short* __restrict__ A,
    const unsigned short* __restrict__ Bt,
    const float* __restrict__ bias,
    void* __restrict__ Cout,
    int M, int Nn, int K, int ldc)
{
    __shared__ unsigned short lds[8192];        // As[128][32] ++ Bs[128][32]
    const int tid = threadIdx.x;
    const int w = tid >> 6, lane = tid & 63;
    const int lk = lane & 15, lg = lane >> 4;
    const int nbn = Nn >> 7;
    const int nb = gridDim.x;
    int bid = blockIdx.x;
    int swz = (nb & 7) ? bid : (bid & 7) * (nb >> 3) + (bid >> 3);  // XCD swizzle
    const int bm = (swz / nbn) << 7, bn = (swz % nbn) << 7;
    const int wr = w >> 1, wc = w & 1;
    const int srow = lane >> 2;                 // 0..15
    const int skoff = (lane & 3) << 3;          // 0,8,16,24 (bf16 elems)

    f32x4 acc[4][4] = {};

    for (int k0 = 0; k0 < K; k0 += 32) {
        #pragma unroll
        for (int i = 0; i < 4; ++i) {           // chunk c: 1KB, wave-linear dest
            int c = i * 4 + w;
            const unsigned short* gp = (c < 8)
                ? A  + (size_t)(bm + c * 16 + srow) * K + k0 + skoff
                : Bt + (size_t)(bn + (c - 8) * 16 + srow) * K + k0 + skoff;
            GLL16(gp, &lds[c * 512 + lane * 8]);
        }
        __syncthreads();                        // compiler drains vmcnt first

        bf16x8 af[4], bfr[4];
        #pragma unroll
        for (int m = 0; m < 4; ++m)
            af[m] = *(const bf16x8*)&lds[(wr * 64 + m * 16 + lk) * 32 + lg * 8];
        #pragma unroll
        for (int n = 0; n < 4; ++n)
            bfr[n] = *(const bf16x8*)&lds[4096 + (wc * 64 + n * 16 + lk) * 32 + lg * 8];
        #pragma unroll
        for (int m = 0; m < 4; ++m)
            #pragma unroll
            for (int n = 0; n < 4; ++n)
                acc[m][n] = __builtin_amdgcn_mfma_f32_16x16x32_bf16(af[m], bfr[n], acc[m][n], 0, 0, 0);
        __syncthreads();
    }

    #pragma unroll
    for (int m = 0; m < 4; ++m) {
        int row = bm + wr * 64 + m * 16 + lg * 4;
        #pragma unroll
        for (int n = 0; n < 4; ++n) {
            int col = bn + wc * 64 + n * 16 + lk;
            #pragma unroll
            for (int r = 0; r < 4; ++r) {
                float v = acc[m][n][r];
                if (EPI >= 1) v += bias[col];
                if (EPI == 2) v = 0.5f * v * (1.0f + erff(v * 0.7071067811865475f));
                if (OUT_BF)
                    ((unsigned short*)Cout)[(size_t)(row + r) * ldc + col] = f2bf(v);
                else
                    ((float*)Cout)[(size_t)(row + r) * ldc + col] = v;
            }
        }
    }
}

// ---------------------------------------------------------------------------
// fp32 -> bf16 flat convert, 4 elems/thread
// ---------------------------------------------------------------------------
__global__ __launch_bounds__(256) void cvt_bf16(
    const float* __restrict__ src, unsigned short* __restrict__ dst, int n)
{
    int i = (blockIdx.x * 256 + threadIdx.x) * 4;
    if (i < n) {
        float4 v = *(const float4*)(src + i);
        u16x4 o = { f2bf(v.x), f2bf(v.y), f2bf(v.z), f2bf(v.w) };
        *(u16x4*)(dst + i) = o;
    }
}

// ---------------------------------------------------------------------------
// transpose + convert: src [R][Cc] f32 -> dst [Cc][R] bf16 (for B^T weights)
// ---------------------------------------------------------------------------
__global__ __launch_bounds__(256) void transpose_cvt(
    const float* __restrict__ src, unsigned short* __restrict__ dst, int R, int Cc)
{
    __shared__ float t[32][33];
    const int bc = blockIdx.x * 32, br = blockIdx.y * 32;
    const int tx = threadIdx.x & 31, ty = threadIdx.x >> 5;
    #pragma unroll
    for (int i = 0; i < 4; ++i)
        t[ty + i * 8][tx] = src[(size_t)(br + ty + i * 8) * Cc + bc + tx];
    __syncthreads();
    #pragma unroll
    for (int i = 0; i < 4; ++i)
        dst[(size_t)(bc + ty + i * 8) * R + br + tx] = f2bf(t[tx][ty + i * 8]);
}

// ---------------------------------------------------------------------------
// drofe on packed QK buffer: rows B*N, row stride 2048 f32 (Q cols 0..1023,
// K cols 1024..2047), in place.
// ---------------------------------------------------------------------------
__global__ __launch_bounds__(256) void drofe_kernel(
    float* __restrict__ QK,
    const float* __restrict__ freqband, const float* __restrict__ demo,
    int B, int N)
{
    const float PI_F = 3.14159265358979323846f;
    int idx = blockIdx.x * 256 + threadIdx.x;   // B*N*512 total
    int col2 = idx & 511;
    int row  = idx >> 9;
    int n = row & (N - 1), b = row / N;
    int i  = col2 & 31;
    int ii = (i < 16) ? i : i - 16;
    float fb = (i < 16) ? freqband[n * 2 + 0] : freqband[n * 2 + 1];
    float freq = (1.0f + (float)ii * (4.0f / 15.0f)) * PI_F;
    float ang = fb * freq;
    float cv = cosf(ang), sv = sinf(ang);
    float ca = cv * demo[b * 2 + 0];
    float sg = sv * demo[b * 2 + 1];
    float2* p = (float2*)QK + (size_t)row * 1024;
    float2 q = p[col2];
    float2 k = p[512 + col2];
    p[col2]       = make_float2(q.x * ca - q.y * sg, q.y * ca + q.x * sg);
    p[512 + col2] = make_float2(k.x * ca - k.y * sg, k.y * ca + k.x * sg);
}

// ---------------------------------------------------------------------------
// Flash attention, bf16 MFMA (16x16x32), fp32 accum. Q/K row stride ldq,
// V row stride ldv; O written bf16 (row stride 1024).
// ---------------------------------------------------------------------------
#define LDK 72

__global__ __launch_bounds__(256) void attn_mfma(
    const float* __restrict__ Q, const float* __restrict__ K,
    const float* __restrict__ V, unsigned short* __restrict__ O,
    int B, int H, int N, int ldq, int ldv)
{
    __shared__ unsigned short Ks[64 * LDK];
    __shared__ unsigned short Vt[64 * LDK];
    __shared__ unsigned short Ps[4][16 * LDK];

    const int nqb = N / 64;
    const int bh = blockIdx.x / nqb;
    const int q0 = (blockIdx.x % nqb) * 64;
    const int b = bh / H, h = bh % H;
    const int tid = threadIdx.x;
    const int w = tid >> 6, lane = tid & 63;
    const int lg = lane >> 4, lk = lane & 15;
    const float scale = 0.125f;

    bf16x8 qf[2];
    {
        const float* qrow = Q + (size_t)(b * N + q0 + w * 16 + lk) * ldq + h * 64;
        #pragma unroll
        for (int kh = 0; kh < 2; ++kh)
            #pragma unroll
            for (int j = 0; j < 8; ++j)
                qf[kh][j] = (short)f2bf(qrow[kh * 32 + lg * 8 + j] * scale);
    }

    f32x4 o[4] = {};
    float mrow[4], lrow[4];
    #pragma unroll
    for (int r = 0; r < 4; ++r) { mrow[r] = -INFINITY; lrow[r] = 0.f; }

    for (int t0 = 0; t0 < N; t0 += 64) {
        for (int i = tid; i < 64 * 64; i += 256) {
            int k = i >> 6, d = i & 63;
            Ks[k * LDK + d] = f2bf(K[(size_t)(b * N + t0 + k) * ldq + h * 64 + d]);
            Vt[d * LDK + k] = f2bf(V[(size_t)(b * N + t0 + k) * ldv + h * 64 + d]);
        }
        __syncthreads();

        f32x4 s[4];
        #pragma unroll
        for (int sub = 0; sub < 4; ++sub) {
            f32x4 acc = {0.f, 0.f, 0.f, 0.f};
            #pragma unroll
            for (int kh = 0; kh < 2; ++kh) {
                bf16x8 kf = *(const bf16x8*)(&Ks[(sub * 16 + lk) * LDK + kh * 32 + lg * 8]);
                acc = __builtin_amdgcn_mfma_f32_16x16x32_bf16(qf[kh], kf, acc, 0, 0, 0);
            }
            s[sub] = acc;
        }

        #pragma unroll
        for (int r = 0; r < 4; ++r) {
            float tm = fmaxf(fmaxf(s[0][r], s[1][r]), fmaxf(s[2][r], s[3][r]));
            #pragma unroll
            for (int msk = 1; msk < 16; msk <<= 1) tm = fmaxf(tm, __shfl_xor(tm, msk));
            float mn = fmaxf(mrow[r], tm);
            float corr = __expf(mrow[r] - mn);
            mrow[r] = mn;
            float psum = 0.f;
            unsigned short pb[4];
            #pragma unroll
            for (int sub = 0; sub < 4; ++sub) {
                float p = __expf(s[sub][r] - mn);
                psum += p;
                pb[sub] = f2bf(p);
            }
            #pragma unroll
            for (int msk = 1; msk < 16; msk <<= 1) psum += __shfl_xor(psum, msk);
            lrow[r] = lrow[r] * corr + psum;
            #pragma unroll
            for (int ds = 0; ds < 4; ++ds) o[ds][r] *= corr;
            int q = lg * 4 + r;
            #pragma unroll
            for (int sub = 0; sub < 4; ++sub)
                Ps[w][q * LDK + sub * 16 + lk] = pb[sub];
        }
        asm volatile("s_waitcnt lgkmcnt(0)" ::: "memory");

        #pragma unroll
        for (int kh = 0; kh < 2; ++kh) {
            bf16x8 pf = *(const bf16x8*)(&Ps[w][lk * LDK + kh * 32 + lg * 8]);
            #pragma unroll
            for (int ds = 0; ds < 4; ++ds) {
                bf16x8 vf = *(const bf16x8*)(&Vt[(ds * 16 + lk) * LDK + kh * 32 + lg * 8]);
                o[ds] = __builtin_amdgcn_mfma_f32_16x16x32_bf16(pf, vf, o[ds], 0, 0, 0);
            }
        }
        __syncthreads();
    }

    #pragma unroll
    for (int ds = 0; ds < 4; ++ds)
        #pragma unroll
        for (int r = 0; r < 4; ++r) {
            int q = lg * 4 + r;
            O[(size_t)(b * N + q0 + w * 16 + q) * 1024 + h * 64 + ds * 16 + lk] =
                f2bf(o[ds][r] / lrow[r]);
        }
}

// ---------------------------------------------------------------------------
// Fused residual + LayerNorm: out = LN(x + gamma*y) * w + b  (+ optional bf16)
// ---------------------------------------------------------------------------
__global__ __launch_bounds__(256) void ln_res_kernel(
    const float* __restrict__ x, const float* __restrict__ y,
    const float* __restrict__ gamma, const float* __restrict__ w,
    const float* __restrict__ bia, float* __restrict__ out,
    unsigned short* __restrict__ out_bf, int C)
{
    const int row = blockIdx.x;
    __shared__ float buf[1024];
    __shared__ float red[8];
    const size_t base = (size_t)row * C;
    float s = 0.f, ss = 0.f;
    for (int c = threadIdx.x; c < C; c += 256) {
        float v = x[base + c] + gamma[c] * y[base + c];
        buf[c] = v; s += v; ss += v * v;
    }
    #pragma unroll
    for (int msk = 1; msk < 64; msk <<= 1) { s += __shfl_xor(s, msk); ss += __shfl_xor(ss, msk); }
    int wv = threadIdx.x >> 6, lane = threadIdx.x & 63;
    if (lane == 0) { red[wv * 2] = s; red[wv * 2 + 1] = ss; }
    __syncthreads();
    if (threadIdx.x == 0) {
        float S = 0.f, SS = 0.f;
        #pragma unroll
        for (int i = 0; i < 4; ++i) { S += red[2 * i]; SS += red[2 * i + 1]; }
        red[0] = S; red[1] = SS;
    }
    __syncthreads();
    float mu = red[0] / C;
    float var = red[1] / C - mu * mu;
    float rstd = rsqrtf(var + 1e-5f);
    for (int c = threadIdx.x; c < C; c += 256) {
        float v = (buf[c] - mu) * rstd * w[c] + bia[c];
        out[base + c] = v;
        if (out_bf) out_bf[base + c] = f2bf(v);
    }
}

// ---------------------------------------------------------------------------
extern "C" void kernel_launch(void* const* d_in, const int* in_sizes, int n_in,
                              void* d_out, int out_size, void* d_ws, size_t ws_size,
                              hipStream_t stream)
{
    const float* x      = (const float*)d_in[0];
    const float* demo   = (const float*)d_in[1];
    const float* expl   = (const float*)d_in[2];
    const float* fb     = (const float*)d_in[3];
    const float* w_qkv  = (const float*)d_in[4];
    const float* w_proj = (const float*)d_in[5];
    const float* b_proj = (const float*)d_in[6];
    const float* gamma1 = (const float*)d_in[7];
    const float* gamma2 = (const float*)d_in[8];
    const float* ln1_w  = (const float*)d_in[9];
    const float* ln1_b  = (const float*)d_in[10];
    const float* ln2_w  = (const float*)d_in[11];
    const float* ln2_b  = (const float*)d_in[12];
    const float* w1     = (const float*)d_in[13];
    const float* b1     = (const float*)d_in[14];
    const float* w2     = (const float*)d_in[15];
    const float* b2     = (const float*)d_in[16];
    float* out = (float*)d_out;

    const int B = 8, N = 1024, C = 1024, F = 4096, H = 16;
    const int M = B * N;                        // 8192
    const size_t Mi = 1048576;

    // workspace layout (float units), total 54 Mi floats = 216 MB
    float* ws = (float*)d_ws;
    float* QKb = ws;                            // 16Mi f32 (M x 2048)
    float* Vb  = ws + 16 * Mi;                  // 8Mi f32
    unsigned short* Ebf = (unsigned short*)(ws + 24 * Mi);   // 8Mi bf16
    unsigned short* Xbf = (unsigned short*)(ws + 28 * Mi);   // 8Mi bf16
    unsigned short* Hid = (unsigned short*)(ws + 32 * Mi);   // 32Mi bf16 (M x F)
    unsigned short* Wt  = (unsigned short*)(ws + 48 * Mi);   // 12Mi bf16 weights
    unsigned short* wqkvT = Wt;                 // [3072][1024]
    unsigned short* wprojT = Wt + 3 * Mi;       // [1024][1024]
    unsigned short* w1T = Wt + 4 * Mi;          // [4096][1024]
    unsigned short* w2T = Wt + 8 * Mi;          // [1024][4096]
    float* Pb = QKb;                            // reuse
    float* H2 = QKb + 8 * Mi;
    float* X1 = Vb;
    unsigned short* Obf  = Ebf;
    unsigned short* X1bf = Xbf;

    dim3 blk(256);
    const int MC = M * C;                       // 8388608

    // bf16 conversions
    hipLaunchKernelGGL(cvt_bf16, dim3(MC / 1024), blk, 0, stream, expl, Ebf, MC);
    hipLaunchKernelGGL(cvt_bf16, dim3(MC / 1024), blk, 0, stream, x, Xbf, MC);
    hipLaunchKernelGGL(transpose_cvt, dim3(96, 32), blk, 0, stream, w_qkv, wqkvT, C, 3 * C);
    hipLaunchKernelGGL(transpose_cvt, dim3(32, 32), blk, 0, stream, w_proj, wprojT, C, C);
    hipLaunchKernelGGL(transpose_cvt, dim3(128, 32), blk, 0, stream, w1, w1T, C, F);
    hipLaunchKernelGGL(transpose_cvt, dim3(32, 128), blk, 0, stream, w2, w2T, F, C);

    // QK projection (from explanation) and V projection (from x)
    hipLaunchKernelGGL((gemm_bf<0,0>), dim3(64 * 16), blk, 0, stream, Ebf, wqkvT, (const float*)nullptr, (void*)QKb, M, 2048, C, 2048);
    hipLaunchKernelGGL((gemm_bf<0,0>), dim3(64 * 8), blk, 0, stream, Xbf, wqkvT + (size_t)2048 * 1024, (const float*)nullptr, (void*)Vb, M, 1024, C, 1024);

    // drofe in place on QKb
    hipLaunchKernelGGL(drofe_kernel, dim3(M * 512 / 256), blk, 0, stream, QKb, fb, demo, B, N);

    // attention -> bf16 O
    hipLaunchKernelGGL(attn_mfma, dim3(B * H * (N / 64)), blk, 0, stream, QKb, QKb + 1024, Vb, Obf, B, H, N, 2048, 1024);

    // output projection
    hipLaunchKernelGGL((gemm_bf<1,0>), dim3(64 * 8), blk, 0, stream, Obf, wprojT, b_proj, (void*)Pb, M, 1024, C, 1024);

    // residual + LN1 (fp32 + bf16 outputs)
    hipLaunchKernelGGL(ln_res_kernel, dim3(M), blk, 0, stream, x, Pb, gamma1, ln1_w, ln1_b, X1, X1bf, C);

    // MLP
    hipLaunchKernelGGL((gemm_bf<2,1>), dim3(64 * 32), blk, 0, stream, X1bf, w1T, b1, (void*)Hid, M, F, C, F);
    hipLaunchKernelGGL((gemm_bf<1,0>), dim3(64 * 8), blk, 0, stream, Hid, w2T, b2, (void*)H2, M, 1024, F, 1024);

    // residual + LN2 -> out
    hipLaunchKernelGGL(ln_res_kernel, dim3(M), blk, 0, stream, X1, H2, gamma2, ln2_w, ln2_b, out, (unsigned short*)nullptr, C);
}

// Round 4
// 536.701 us; speedup vs baseline: 11.1746x; 1.1801x over previous
//
#include <hip/hip_runtime.h>
#include <hip/hip_bf16.h>
#include <math.h>

typedef __attribute__((ext_vector_type(8))) short bf16x8;
typedef __attribute__((ext_vector_type(8))) unsigned short u16x8;
typedef __attribute__((ext_vector_type(4))) float f32x4;
typedef __attribute__((ext_vector_type(4))) unsigned short u16x4;

__device__ inline unsigned short f2bf(float f) {
    union { float f; unsigned u; } v; v.f = f;
    unsigned r = (v.u + 0x7fff + ((v.u >> 16) & 1)) >> 16;   // RNE
    return (unsigned short)r;
}
__device__ inline float bf2f(unsigned short u) {
    union { unsigned u; float f; } v; v.u = ((unsigned)u) << 16; return v.f;
}

#define GLL16(gp, lp) __builtin_amdgcn_global_load_lds(                      \
    (const __attribute__((address_space(1))) void*)(gp),                     \
    (__attribute__((address_space(3))) void*)(lp), 16, 0, 0)

// ---------------------------------------------------------------------------
// bf16 MFMA GEMM, m97 structure: 128x128 tile, BK=32, 4 waves (2x2), each wave
// 64x64 = 4x4 frags of 16x16x32. A [M][K] bf16, Bt [N][K] bf16 (B transposed),
// both staged k-contiguous in LDS via global_load_lds width=16.
// EPI: 0=none 1=+bias 2=+bias+gelu(exact). OUT_BF: write bf16 instead of f32.
// ---------------------------------------------------------------------------
template<int EPI, int OUT_BF>
__global__ __launch_bounds__(256) void gemm_bf(
    const unsigned short* __restrict__ A,
    const unsigned short* __restrict__ Bt,
    const float* __restrict__ bias,
    void* __restrict__ Cout,
    int M, int Nn, int K, int ldc)
{
    __shared__ unsigned short lds[8192];        // As[128][32] ++ Bs[128][32]
    const int tid = threadIdx.x;
    const int w = tid >> 6, lane = tid & 63;
    const int lk = lane & 15, lg = lane >> 4;
    const int nbn = Nn >> 7;
    const int nb = gridDim.x;
    int bid = blockIdx.x;
    int swz = (nb & 7) ? bid : (bid & 7) * (nb >> 3) + (bid >> 3);  // XCD swizzle
    const int bm = (swz / nbn) << 7, bn = (swz % nbn) << 7;
    const int wr = w >> 1, wc = w & 1;
    const int srow = lane >> 2;                 // 0..15
    const int skoff = (lane & 3) << 3;          // 0,8,16,24 (bf16 elems)

    f32x4 acc[4][4] = {};

    for (int k0 = 0; k0 < K; k0 += 32) {
        #pragma unroll
        for (int i = 0; i < 4; ++i) {           // chunk c: 1KB, wave-linear dest
            int c = i * 4 + w;
            const unsigned short* gp = (c < 8)
                ? A  + (size_t)(bm + c * 16 + srow) * K + k0 + skoff
                : Bt + (size_t)(bn + (c - 8) * 16 + srow) * K + k0 + skoff;
            GLL16(gp, &lds[c * 512 + lane * 8]);
        }
        __syncthreads();                        // compiler drains vmcnt first

        bf16x8 af[4], bfr[4];
        #pragma unroll
        for (int m = 0; m < 4; ++m)
            af[m] = *(const bf16x8*)&lds[(wr * 64 + m * 16 + lk) * 32 + lg * 8];
        #pragma unroll
        for (int n = 0; n < 4; ++n)
            bfr[n] = *(const bf16x8*)&lds[4096 + (wc * 64 + n * 16 + lk) * 32 + lg * 8];
        #pragma unroll
        for (int m = 0; m < 4; ++m)
            #pragma unroll
            for (int n = 0; n < 4; ++n)
                acc[m][n] = __builtin_amdgcn_mfma_f32_16x16x32_bf16(af[m], bfr[n], acc[m][n], 0, 0, 0);
        __syncthreads();
    }

    #pragma unroll
    for (int m = 0; m < 4; ++m) {
        int row = bm + wr * 64 + m * 16 + lg * 4;
        #pragma unroll
        for (int n = 0; n < 4; ++n) {
            int col = bn + wc * 64 + n * 16 + lk;
            #pragma unroll
            for (int r = 0; r < 4; ++r) {
                float v = acc[m][n][r];
                if (EPI >= 1) v += bias[col];
                if (EPI == 2) v = 0.5f * v * (1.0f + erff(v * 0.7071067811865475f));
                if (OUT_BF)
                    ((unsigned short*)Cout)[(size_t)(row + r) * ldc + col] = f2bf(v);
                else
                    ((float*)Cout)[(size_t)(row + r) * ldc + col] = v;
            }
        }
    }
}

// ---------------------------------------------------------------------------
// fp32 -> bf16 flat convert, 4 elems/thread
// ---------------------------------------------------------------------------
__global__ __launch_bounds__(256) void cvt_bf16(
    const float* __restrict__ src, unsigned short* __restrict__ dst, int n)
{
    int i = (blockIdx.x * 256 + threadIdx.x) * 4;
    if (i < n) {
        float4 v = *(const float4*)(src + i);
        u16x4 o = { f2bf(v.x), f2bf(v.y), f2bf(v.z), f2bf(v.w) };
        *(u16x4*)(dst + i) = o;
    }
}

// ---------------------------------------------------------------------------
// transpose + convert: src [R][Cc] f32 -> dst [Cc][R] bf16 (for B^T weights)
// ---------------------------------------------------------------------------
__global__ __launch_bounds__(256) void transpose_cvt(
    const float* __restrict__ src, unsigned short* __restrict__ dst, int R, int Cc)
{
    __shared__ float t[32][33];
    const int bc = blockIdx.x * 32, br = blockIdx.y * 32;
    const int tx = threadIdx.x & 31, ty = threadIdx.x >> 5;
    #pragma unroll
    for (int i = 0; i < 4; ++i)
        t[ty + i * 8][tx] = src[(size_t)(br + ty + i * 8) * Cc + bc + tx];
    __syncthreads();
    #pragma unroll
    for (int i = 0; i < 4; ++i)
        dst[(size_t)(bc + ty + i * 8) * R + br + tx] = f2bf(t[tx][ty + i * 8]);
}

// ---------------------------------------------------------------------------
// drofe on bf16 QK [M][2048] -> rotated bf16 Q [M][1024] (scale 0.125 folded)
// and K [M][1024]. One thread per even/odd pair.
// ---------------------------------------------------------------------------
__global__ __launch_bounds__(256) void drofe_bf(
    const unsigned short* __restrict__ QK, unsigned short* __restrict__ Qo,
    unsigned short* __restrict__ Ko,
    const float* __restrict__ freqband, const float* __restrict__ demo, int N)
{
    const float PI_F = 3.14159265358979323846f;
    int idx = blockIdx.x * 256 + threadIdx.x;   // B*N*512 threads
    int col2 = idx & 511;
    int row  = idx >> 9;
    int n = row & (N - 1), b = row >> 10;       // N=1024
    int i  = col2 & 31;
    int ii = (i < 16) ? i : i - 16;
    float fb = (i < 16) ? freqband[n * 2 + 0] : freqband[n * 2 + 1];
    float freq = (1.0f + (float)ii * (4.0f / 15.0f)) * PI_F;
    float ang = fb * freq;
    float cv = cosf(ang), sv = sinf(ang);
    float ca = cv * demo[b * 2 + 0];
    float sg = sv * demo[b * 2 + 1];
    const unsigned* qk = (const unsigned*)(QK + (size_t)row * 2048);
    unsigned qu = qk[col2], ku = qk[512 + col2];
    float qe = bf2f((unsigned short)qu), qo_ = bf2f((unsigned short)(qu >> 16));
    float ke = bf2f((unsigned short)ku), ko_ = bf2f((unsigned short)(ku >> 16));
    const float s8 = 0.125f;
    unsigned qres = (unsigned)f2bf((qe * ca - qo_ * sg) * s8)
                  | ((unsigned)f2bf((qo_ * ca + qe * sg) * s8) << 16);
    unsigned kres = (unsigned)f2bf(ke * ca - ko_ * sg)
                  | ((unsigned)f2bf(ko_ * ca + ke * sg) << 16);
    ((unsigned*)Qo)[(size_t)row * 512 + col2] = qres;
    ((unsigned*)Ko)[(size_t)row * 512 + col2] = kres;
}

// ---------------------------------------------------------------------------
// Flash attention, bf16 in/out, MFMA 16x16x32, fp32 accum.
// Block = 4 waves, 64 q-rows of one (b,h); 16 key-tiles of 64.
// K: global_load_lds into linear [64][64] bf16 with XOR-swizzle pair
//    (inverse-swizzled global source, swizzled ds_read_b128) -> conflict-free.
// V: reg-staged transposed [d][72] (b32 packed writes, k-contiguous across
//    lanes = conflict-free); PV fragments are clean ds_read_b128.
// Block mapping: all 16 q-blocks of a (b,h) land on one XCD for K/V L2 reuse.
// ---------------------------------------------------------------------------
__global__ __launch_bounds__(256) void attn_mfma(
    const unsigned short* __restrict__ Q, const unsigned short* __restrict__ K,
    const unsigned short* __restrict__ V, unsigned short* __restrict__ O,
    int B, int H, int N)
{
    __shared__ unsigned short Ks[64 * 64];
    __shared__ unsigned short Vt[64 * 72];
    __shared__ unsigned short Ps[4][16 * 72];

    const int bi = blockIdx.x;                  // 2048
    const int bh = (bi & 7) + 8 * ((bi >> 3) & 15);   // same bh -> same XCD
    const int q0 = (bi >> 7) * 64;
    const int b = bh >> 4, h = bh & 15;         // H = 16
    const int tid = threadIdx.x;
    const int w = tid >> 6, lane = tid & 63;
    const int lg = lane >> 4, lk = lane & 15;

    bf16x8 qf[2];                               // scale pre-folded in drofe
    {
        const unsigned short* qrow = Q + (size_t)(b * N + q0 + w * 16 + lk) * 1024 + h * 64;
        qf[0] = *(const bf16x8*)(qrow + lg * 8);
        qf[1] = *(const bf16x8*)(qrow + 32 + lg * 8);
    }

    f32x4 o[4] = {};
    float mrow[4], lrow[4];
    #pragma unroll
    for (int r = 0; r < 4; ++r) { mrow[r] = -INFINITY; lrow[r] = 0.f; }

    for (int t0 = 0; t0 < N; t0 += 64) {
        const size_t kvbase = (size_t)(b * N + t0) * 1024 + h * 64;
        #pragma unroll
        for (int it = 0; it < 2; ++it) {        // K: 512 slots x 16B, swz source
            int s = it * 256 + tid;
            int row = s >> 3, cb = (s & 7) << 4;
            int dby = cb ^ ((row & 7) << 4);
            GLL16(K + kvbase + (size_t)row * 1024 + (dby >> 1), &Ks[s * 8]);
        }
        {                                       // V: reg-staged transpose
            int c = tid >> 5, k0 = (tid & 31) * 2;
            const unsigned short* vp = V + kvbase + (size_t)k0 * 1024 + c * 8;
            u16x8 va = *(const u16x8*)vp;
            u16x8 vb = *(const u16x8*)(vp + 1024);
            #pragma unroll
            for (int j = 0; j < 8; ++j) {
                unsigned val = (unsigned)va[j] | ((unsigned)vb[j] << 16);
                *(unsigned*)&Vt[(c * 8 + j) * 72 + k0] = val;
            }
        }
        __syncthreads();

        // S = Q K^T : key = sub*16+lk (C cols), q = lg*4+r (C rows)
        f32x4 s4[4];
        #pragma unroll
        for (int sub = 0; sub < 4; ++sub) {
            f32x4 acc = {0.f, 0.f, 0.f, 0.f};
            #pragma unroll
            for (int kh = 0; kh < 2; ++kh) {
                int cc = (kh * 64 + lg * 16) ^ ((lk & 7) << 4);
                bf16x8 kf = *(const bf16x8*)&Ks[(sub * 16 + lk) * 64 + (cc >> 1)];
                acc = __builtin_amdgcn_mfma_f32_16x16x32_bf16(qf[kh], kf, acc, 0, 0, 0);
            }
            s4[sub] = acc;
        }

        // online softmax
        #pragma unroll
        for (int r = 0; r < 4; ++r) {
            float tm = fmaxf(fmaxf(s4[0][r], s4[1][r]), fmaxf(s4[2][r], s4[3][r]));
            #pragma unroll
            for (int msk = 1; msk < 16; msk <<= 1) tm = fmaxf(tm, __shfl_xor(tm, msk));
            float mn = fmaxf(mrow[r], tm);
            float corr = __expf(mrow[r] - mn);
            mrow[r] = mn;
            float psum = 0.f;
            unsigned short pb[4];
            #pragma unroll
            for (int sub = 0; sub < 4; ++sub) {
                float p = __expf(s4[sub][r] - mn);
                psum += p;
                pb[sub] = f2bf(p);
            }
            #pragma unroll
            for (int msk = 1; msk < 16; msk <<= 1) psum += __shfl_xor(psum, msk);
            lrow[r] = lrow[r] * corr + psum;
            #pragma unroll
            for (int ds = 0; ds < 4; ++ds) o[ds][r] *= corr;
            int q = lg * 4 + r;
            #pragma unroll
            for (int sub = 0; sub < 4; ++sub)
                Ps[w][q * 72 + sub * 16 + lk] = pb[sub];
        }
        asm volatile("s_waitcnt lgkmcnt(0)" ::: "memory");   // per-wave P RAW

        // O += P V : A=P (row=lk=q, k=key), B=V^T (col=lk=d-local, k=key)
        #pragma unroll
        for (int kh = 0; kh < 2; ++kh) {
            bf16x8 pf = *(const bf16x8*)&Ps[w][lk * 72 + kh * 32 + lg * 8];
            #pragma unroll
            for (int ds = 0; ds < 4; ++ds) {
                bf16x8 vf = *(const bf16x8*)&Vt[(ds * 16 + lk) * 72 + kh * 32 + lg * 8];
                o[ds] = __builtin_amdgcn_mfma_f32_16x16x32_bf16(pf, vf, o[ds], 0, 0, 0);
            }
        }
        __syncthreads();
    }

    #pragma unroll
    for (int ds = 0; ds < 4; ++ds)
        #pragma unroll
        for (int r = 0; r < 4; ++r) {
            int q = lg * 4 + r;
            O[(size_t)(b * N + q0 + w * 16 + q) * 1024 + h * 64 + ds * 16 + lk] =
                f2bf(o[ds][r] / lrow[r]);
        }
}

// ---------------------------------------------------------------------------
// Fused residual + LayerNorm: out = LN(x + gamma*y) * w + b  (+ optional bf16)
// ---------------------------------------------------------------------------
__global__ __launch_bounds__(256) void ln_res_kernel(
    const float* __restrict__ x, const float* __restrict__ y,
    const float* __restrict__ gamma, const float* __restrict__ w,
    const float* __restrict__ bia, float* __restrict__ out,
    unsigned short* __restrict__ out_bf, int C)
{
    const int row = blockIdx.x;
    __shared__ float buf[1024];
    __shared__ float red[8];
    const size_t base = (size_t)row * C;
    float s = 0.f, ss = 0.f;
    for (int c = threadIdx.x; c < C; c += 256) {
        float v = x[base + c] + gamma[c] * y[base + c];
        buf[c] = v; s += v; ss += v * v;
    }
    #pragma unroll
    for (int msk = 1; msk < 64; msk <<= 1) { s += __shfl_xor(s, msk); ss += __shfl_xor(ss, msk); }
    int wv = threadIdx.x >> 6, lane = threadIdx.x & 63;
    if (lane == 0) { red[wv * 2] = s; red[wv * 2 + 1] = ss; }
    __syncthreads();
    if (threadIdx.x == 0) {
        float S = 0.f, SS = 0.f;
        #pragma unroll
        for (int i = 0; i < 4; ++i) { S += red[2 * i]; SS += red[2 * i + 1]; }
        red[0] = S; red[1] = SS;
    }
    __syncthreads();
    float mu = red[0] / C;
    float var = red[1] / C - mu * mu;
    float rstd = rsqrtf(var + 1e-5f);
    for (int c = threadIdx.x; c < C; c += 256) {
        float v = (buf[c] - mu) * rstd * w[c] + bia[c];
        out[base + c] = v;
        if (out_bf) out_bf[base + c] = f2bf(v);
    }
}

// ---------------------------------------------------------------------------
extern "C" void kernel_launch(void* const* d_in, const int* in_sizes, int n_in,
                              void* d_out, int out_size, void* d_ws, size_t ws_size,
                              hipStream_t stream)
{
    const float* x      = (const float*)d_in[0];
    const float* demo   = (const float*)d_in[1];
    const float* expl   = (const float*)d_in[2];
    const float* fb     = (const float*)d_in[3];
    const float* w_qkv  = (const float*)d_in[4];
    const float* w_proj = (const float*)d_in[5];
    const float* b_proj = (const float*)d_in[6];
    const float* gamma1 = (const float*)d_in[7];
    const float* gamma2 = (const float*)d_in[8];
    const float* ln1_w  = (const float*)d_in[9];
    const float* ln1_b  = (const float*)d_in[10];
    const float* ln2_w  = (const float*)d_in[11];
    const float* ln2_b  = (const float*)d_in[12];
    const float* w1     = (const float*)d_in[13];
    const float* b1     = (const float*)d_in[14];
    const float* w2     = (const float*)d_in[15];
    const float* b2     = (const float*)d_in[16];
    float* out = (float*)d_out;

    const int B = 8, N = 1024, C = 1024, F = 4096, H = 16;
    const int M = B * N;                        // 8192
    const size_t Mi = 1048576;

    // workspace layout (float units), total ~50.3 Mi floats = 201 MB.
    // Aliasing by lifetime: QKbf(dead after drofe) -> Obf(dead after proj) -> H2
    //                       Ebf/Xbf(dead after V gemm) -> Pb
    //                       Qbf/Kbf/Vbf(dead after attn) -> Hid
    float* ws = (float*)d_ws;
    unsigned short* QKbf = (unsigned short*)ws;              // M x 2048 bf16
    unsigned short* Obf  = (unsigned short*)ws;              // M x 1024 bf16
    float*          H2   = ws;                               // M x 1024 f32
    unsigned short* Qbf  = (unsigned short*)(ws + 8 * Mi);   // M x 1024 bf16
    unsigned short* Kbf  = (unsigned short*)(ws + 12 * Mi);
    unsigned short* Vbf  = (unsigned short*)(ws + 16 * Mi);
    unsigned short* Hid  = (unsigned short*)(ws + 8 * Mi);   // M x 4096 bf16
    unsigned short* Ebf  = (unsigned short*)(ws + 24 * Mi);
    unsigned short* Xbf  = (unsigned short*)(ws + 28 * Mi);
    float*          Pb   = ws + 24 * Mi;                     // M x 1024 f32
    float*          X1   = ws + 32 * Mi;                     // M x 1024 f32
    unsigned short* X1bf = (unsigned short*)(ws + 40 * Mi);
    unsigned short* Wt   = (unsigned short*)(ws + 44 * Mi);
    unsigned short* wqkvT  = Wt;                             // [3072][1024]
    unsigned short* wprojT = Wt + (size_t)3145728;           // [1024][1024]
    unsigned short* w1T    = wprojT + (size_t)1048576;       // [4096][1024]
    unsigned short* w2T    = w1T + (size_t)4194304;          // [1024][4096]

    dim3 blk(256);
    const int MC = M * C;

    hipLaunchKernelGGL(cvt_bf16, dim3(MC / 1024), blk, 0, stream, expl, Ebf, MC);
    hipLaunchKernelGGL(cvt_bf16, dim3(MC / 1024), blk, 0, stream, x, Xbf, MC);
    hipLaunchKernelGGL(transpose_cvt, dim3(96, 32), blk, 0, stream, w_qkv, wqkvT, C, 3 * C);
    hipLaunchKernelGGL(transpose_cvt, dim3(32, 32), blk, 0, stream, w_proj, wprojT, C, C);
    hipLaunchKernelGGL(transpose_cvt, dim3(128, 32), blk, 0, stream, w1, w1T, C, F);
    hipLaunchKernelGGL(transpose_cvt, dim3(32, 128), blk, 0, stream, w2, w2T, F, C);

    // QK projection (explanation) -> bf16; V projection (x) -> bf16
    hipLaunchKernelGGL((gemm_bf<0,1>), dim3(64 * 16), blk, 0, stream, Ebf, wqkvT, (const float*)nullptr, (void*)QKbf, M, 2048, C, 2048);
    hipLaunchKernelGGL((gemm_bf<0,1>), dim3(64 * 8), blk, 0, stream, Xbf, wqkvT + (size_t)2048 * 1024, (const float*)nullptr, (void*)Vbf, M, 1024, C, 1024);

    // drofe: bf16 QK -> rotated bf16 Q (scaled), K
    hipLaunchKernelGGL(drofe_bf, dim3(M * 512 / 256), blk, 0, stream, QKbf, Qbf, Kbf, fb, demo, N);

    // attention -> bf16 O
    hipLaunchKernelGGL(attn_mfma, dim3(B * H * (N / 64)), blk, 0, stream, Qbf, Kbf, Vbf, Obf, B, H, N);

    // output projection
    hipLaunchKernelGGL((gemm_bf<1,0>), dim3(64 * 8), blk, 0, stream, Obf, wprojT, b_proj, (void*)Pb, M, 1024, C, 1024);

    // residual + LN1 (f32 + bf16)
    hipLaunchKernelGGL(ln_res_kernel, dim3(M), blk, 0, stream, x, Pb, gamma1, ln1_w, ln1_b, X1, X1bf, C);

    // MLP
    hipLaunchKernelGGL((gemm_bf<2,1>), dim3(64 * 32), blk, 0, stream, X1bf, w1T, b1, (void*)Hid, M, F, C, F);
    hipLaunchKernelGGL((gemm_bf<1,0>), dim3(64 * 8), blk, 0, stream, Hid, w2T, b2, (void*)H2, M, 1024, F, 1024);

    // residual + LN2 -> out
    hipLaunchKernelGGL(ln_res_kernel, dim3(M), blk, 0, stream, X1, H2, gamma2, ln2_w, ln2_b, out, (unsigned short*)nullptr, C);
}

// Round 5
// 522.204 us; speedup vs baseline: 11.4848x; 1.0278x over previous
//
#include <hip/hip_runtime.h>
#include <hip/hip_bf16.h>
#include <math.h>

typedef __attribute__((ext_vector_type(8))) short bf16x8;
typedef __attribute__((ext_vector_type(8))) unsigned short u16x8;
typedef __attribute__((ext_vector_type(4))) float f32x4;
typedef __attribute__((ext_vector_type(4))) unsigned short u16x4;

__device__ inline unsigned short f2bf(float f) {
    union { float f; unsigned u; } v; v.f = f;
    unsigned r = (v.u + 0x7fff + ((v.u >> 16) & 1)) >> 16;   // RNE
    return (unsigned short)r;
}
__device__ inline float bf2f(unsigned short u) {
    union { unsigned u; float f; } v; v.u = ((unsigned)u) << 16; return v.f;
}

#define GLL16(gp, lp) __builtin_amdgcn_global_load_lds(                      \
    (const __attribute__((address_space(1))) void*)(gp),                     \
    (__attribute__((address_space(3))) void*)(lp), 16, 0, 0)

__device__ inline void block_bar() {
    asm volatile("" ::: "memory");
    __builtin_amdgcn_s_barrier();
    asm volatile("" ::: "memory");
}

// ---------------------------------------------------------------------------
// bf16 MFMA GEMM, 256xBN tile, BK=32, 8 waves (2x4), double-buffered LDS with
// counted vmcnt (loads stay in flight across barriers — no drain-to-0 in loop).
// A [M][K] bf16, Bt [N][K] bf16. LDS rows are 64B, staged via global_load_lds
// (linear dest) with chunk swizzle c^((r>>1)&3) applied on the GLOBAL source
// and on the ds_read address (rule-21 involution) -> slot-uniform b128 reads.
// EPI: 0=none 1=+bias 2=+bias+gelu(exact). OUT_BF: bf16 output.
// ---------------------------------------------------------------------------
template<int EPI, int OUT_BF, int BN>
__global__ __launch_bounds__(512) void gemm2(
    const unsigned short* __restrict__ A,
    const unsigned short* __restrict__ Bt,
    const float* __restrict__ bias,
    void* __restrict__ Cout,
    int M, int Nn, int K, int ldc)
{
    constexpr int ASL = 256 * 4;               // A 16B-slots per tile
    constexpr int BSL = BN * 4;
    constexpr int BUF = (ASL + BSL) * 8;       // ushort elems per buffer
    constexpr int NF  = BN / 64;               // B-frags per wave
    constexpr int NLA = ASL / 512;             // 2 loads/thread (A)
    constexpr int NLB = BSL / 512;             // 2 or 1 (B)
    constexpr int NL  = NLA + NLB;
    __shared__ unsigned short lds[2 * BUF];    // 64 KB (BN=256) / 48 KB (BN=128)

    const int tid = threadIdx.x;
    const int w = tid >> 6, lane = tid & 63;
    const int lk = lane & 15, lg = lane >> 4;
    const int wr = w >> 2, wc = w & 3;         // 2 x 4 wave grid
    const int nbn = Nn / BN;
    const int nb = gridDim.x;
    int bid = blockIdx.x;
    int swz = (nb & 7) ? bid : (bid & 7) * (nb >> 3) + (bid >> 3);  // XCD swizzle
    const int bm = (swz / nbn) << 8;
    const int bn = (swz % nbn) * BN;

    f32x4 acc[8][NF] = {};

    auto stage = [&](int buf, int kt) {
        #pragma unroll
        for (int i = 0; i < NLA; ++i) {
            int sl = tid + i * 512;
            int r = sl >> 2, c = sl & 3;
            int cs = c ^ ((r >> 1) & 3);
            GLL16(A + (size_t)(bm + r) * K + kt + cs * 8, &lds[buf * BUF + sl * 8]);
        }
        #pragma unroll
        for (int i = 0; i < NLB; ++i) {
            int sl = tid + i * 512;
            int r = sl >> 2, c = sl & 3;
            int cs = c ^ ((r >> 1) & 3);
            GLL16(Bt + (size_t)(bn + r) * K + kt + cs * 8,
                  &lds[buf * BUF + ASL * 8 + sl * 8]);
        }
    };

    auto compute = [&](int buf) {
        const unsigned short* as = &lds[buf * BUF];
        const unsigned short* bs = &lds[buf * BUF + ASL * 8];
        bf16x8 af[8]; bf16x8 bfr[NF];
        #pragma unroll
        for (int mi = 0; mi < 8; ++mi) {
            int r = wr * 128 + mi * 16 + lk;
            int cs = lg ^ ((r >> 1) & 3);
            af[mi] = *(const bf16x8*)&as[r * 32 + cs * 8];
        }
        #pragma unroll
        for (int nj = 0; nj < NF; ++nj) {
            int r = wc * (BN / 4) + nj * 16 + lk;
            int cs = lg ^ ((r >> 1) & 3);
            bfr[nj] = *(const bf16x8*)&bs[r * 32 + cs * 8];
        }
        __builtin_amdgcn_s_setprio(1);
        #pragma unroll
        for (int mi = 0; mi < 8; ++mi)
            #pragma unroll
            for (int nj = 0; nj < NF; ++nj)
                acc[mi][nj] = __builtin_amdgcn_mfma_f32_16x16x32_bf16(af[mi], bfr[nj], acc[mi][nj], 0, 0, 0);
        __builtin_amdgcn_s_setprio(0);
    };

    const int NT = K >> 5;
    stage(0, 0);
    int cur = 0;
    for (int t = 0; t < NT - 1; ++t) {
        stage(cur ^ 1, (t + 1) << 5);                    // prefetch next tile
        asm volatile("s_waitcnt vmcnt(%0)" :: "i"(NL) : "memory");  // own cur-tile loads done
        block_bar();                                     // all waves' loads done
        compute(cur);
        block_bar();                                     // cur buf free for overwrite
        cur ^= 1;
    }
    asm volatile("s_waitcnt vmcnt(0)" ::: "memory");
    block_bar();
    compute(cur);

    #pragma unroll
    for (int mi = 0; mi < 8; ++mi) {
        int row = bm + wr * 128 + mi * 16 + lg * 4;
        #pragma unroll
        for (int nj = 0; nj < NF; ++nj) {
            int col = bn + wc * (BN / 4) + nj * 16 + lk;
            #pragma unroll
            for (int r = 0; r < 4; ++r) {
                float v = acc[mi][nj][r];
                if (EPI >= 1) v += bias[col];
                if (EPI == 2) v = 0.5f * v * (1.0f + erff(v * 0.7071067811865475f));
                if (OUT_BF)
                    ((unsigned short*)Cout)[(size_t)(row + r) * ldc + col] = f2bf(v);
                else
                    ((float*)Cout)[(size_t)(row + r) * ldc + col] = v;
            }
        }
    }
}

// ---------------------------------------------------------------------------
// fp32 -> bf16 flat convert, 4 elems/thread
// ---------------------------------------------------------------------------
__global__ __launch_bounds__(256) void cvt_bf16(
    const float* __restrict__ src, unsigned short* __restrict__ dst, int n)
{
    int i = (blockIdx.x * 256 + threadIdx.x) * 4;
    if (i < n) {
        float4 v = *(const float4*)(src + i);
        u16x4 o = { f2bf(v.x), f2bf(v.y), f2bf(v.z), f2bf(v.w) };
        *(u16x4*)(dst + i) = o;
    }
}

// ---------------------------------------------------------------------------
// transpose + convert: src [R][Cc] f32 -> dst [Cc][R] bf16 (for B^T weights)
// ---------------------------------------------------------------------------
__global__ __launch_bounds__(256) void transpose_cvt(
    const float* __restrict__ src, unsigned short* __restrict__ dst, int R, int Cc)
{
    __shared__ float t[32][33];
    const int bc = blockIdx.x * 32, br = blockIdx.y * 32;
    const int tx = threadIdx.x & 31, ty = threadIdx.x >> 5;
    #pragma unroll
    for (int i = 0; i < 4; ++i)
        t[ty + i * 8][tx] = src[(size_t)(br + ty + i * 8) * Cc + bc + tx];
    __syncthreads();
    #pragma unroll
    for (int i = 0; i < 4; ++i)
        dst[(size_t)(bc + ty + i * 8) * R + br + tx] = f2bf(t[tx][ty + i * 8]);
}

// ---------------------------------------------------------------------------
// drofe on bf16 QK [M][2048] -> rotated bf16 Q [M][1024] (scale folded), K.
// ---------------------------------------------------------------------------
__global__ __launch_bounds__(256) void drofe_bf(
    const unsigned short* __restrict__ QK, unsigned short* __restrict__ Qo,
    unsigned short* __restrict__ Ko,
    const float* __restrict__ freqband, const float* __restrict__ demo, int N)
{
    const float PI_F = 3.14159265358979323846f;
    int idx = blockIdx.x * 256 + threadIdx.x;
    int col2 = idx & 511;
    int row  = idx >> 9;
    int n = row & (N - 1), b = row >> 10;
    int i  = col2 & 31;
    int ii = (i < 16) ? i : i - 16;
    float fb = (i < 16) ? freqband[n * 2 + 0] : freqband[n * 2 + 1];
    float freq = (1.0f + (float)ii * (4.0f / 15.0f)) * PI_F;
    float ang = fb * freq;
    float cv = cosf(ang), sv = sinf(ang);
    float ca = cv * demo[b * 2 + 0];
    float sg = sv * demo[b * 2 + 1];
    const unsigned* qk = (const unsigned*)(QK + (size_t)row * 2048);
    unsigned qu = qk[col2], ku = qk[512 + col2];
    float qe = bf2f((unsigned short)qu), qo_ = bf2f((unsigned short)(qu >> 16));
    float ke = bf2f((unsigned short)ku), ko_ = bf2f((unsigned short)(ku >> 16));
    const float s8 = 0.125f;
    unsigned qres = (unsigned)f2bf((qe * ca - qo_ * sg) * s8)
                  | ((unsigned)f2bf((qo_ * ca + qe * sg) * s8) << 16);
    unsigned kres = (unsigned)f2bf(ke * ca - ko_ * sg)
                  | ((unsigned)f2bf(ko_ * ca + ke * sg) << 16);
    ((unsigned*)Qo)[(size_t)row * 512 + col2] = qres;
    ((unsigned*)Ko)[(size_t)row * 512 + col2] = kres;
}

// ---------------------------------------------------------------------------
// Flash attention, bf16 in/out, MFMA 16x16x32, fp32 accum. (round-4 verified)
// ---------------------------------------------------------------------------
__global__ __launch_bounds__(256) void attn_mfma(
    const unsigned short* __restrict__ Q, const unsigned short* __restrict__ K,
    const unsigned short* __restrict__ V, unsigned short* __restrict__ O,
    int B, int H, int N)
{
    __shared__ unsigned short Ks[64 * 64];
    __shared__ unsigned short Vt[64 * 72];
    __shared__ unsigned short Ps[4][16 * 72];

    const int bi = blockIdx.x;
    const int bh = (bi & 7) + 8 * ((bi >> 3) & 15);
    const int q0 = (bi >> 7) * 64;
    const int b = bh >> 4, h = bh & 15;
    const int tid = threadIdx.x;
    const int w = tid >> 6, lane = tid & 63;
    const int lg = lane >> 4, lk = lane & 15;

    bf16x8 qf[2];
    {
        const unsigned short* qrow = Q + (size_t)(b * N + q0 + w * 16 + lk) * 1024 + h * 64;
        qf[0] = *(const bf16x8*)(qrow + lg * 8);
        qf[1] = *(const bf16x8*)(qrow + 32 + lg * 8);
    }

    f32x4 o[4] = {};
    float mrow[4], lrow[4];
    #pragma unroll
    for (int r = 0; r < 4; ++r) { mrow[r] = -INFINITY; lrow[r] = 0.f; }

    for (int t0 = 0; t0 < N; t0 += 64) {
        const size_t kvbase = (size_t)(b * N + t0) * 1024 + h * 64;
        #pragma unroll
        for (int it = 0; it < 2; ++it) {
            int s = it * 256 + tid;
            int row = s >> 3, cb = (s & 7) << 4;
            int dby = cb ^ ((row & 7) << 4);
            GLL16(K + kvbase + (size_t)row * 1024 + (dby >> 1), &Ks[s * 8]);
        }
        {
            int c = tid >> 5, k0 = (tid & 31) * 2;
            const unsigned short* vp = V + kvbase + (size_t)k0 * 1024 + c * 8;
            u16x8 va = *(const u16x8*)vp;
            u16x8 vb = *(const u16x8*)(vp + 1024);
            #pragma unroll
            for (int j = 0; j < 8; ++j) {
                unsigned val = (unsigned)va[j] | ((unsigned)vb[j] << 16);
                *(unsigned*)&Vt[(c * 8 + j) * 72 + k0] = val;
            }
        }
        __syncthreads();

        f32x4 s4[4];
        #pragma unroll
        for (int sub = 0; sub < 4; ++sub) {
            f32x4 acc = {0.f, 0.f, 0.f, 0.f};
            #pragma unroll
            for (int kh = 0; kh < 2; ++kh) {
                int cc = (kh * 64 + lg * 16) ^ ((lk & 7) << 4);
                bf16x8 kf = *(const bf16x8*)&Ks[(sub * 16 + lk) * 64 + (cc >> 1)];
                acc = __builtin_amdgcn_mfma_f32_16x16x32_bf16(qf[kh], kf, acc, 0, 0, 0);
            }
            s4[sub] = acc;
        }

        #pragma unroll
        for (int r = 0; r < 4; ++r) {
            float tm = fmaxf(fmaxf(s4[0][r], s4[1][r]), fmaxf(s4[2][r], s4[3][r]));
            #pragma unroll
            for (int msk = 1; msk < 16; msk <<= 1) tm = fmaxf(tm, __shfl_xor(tm, msk));
            float mn = fmaxf(mrow[r], tm);
            float corr = __expf(mrow[r] - mn);
            mrow[r] = mn;
            float psum = 0.f;
            unsigned short pb[4];
            #pragma unroll
            for (int sub = 0; sub < 4; ++sub) {
                float p = __expf(s4[sub][r] - mn);
                psum += p;
                pb[sub] = f2bf(p);
            }
            #pragma unroll
            for (int msk = 1; msk < 16; msk <<= 1) psum += __shfl_xor(psum, msk);
            lrow[r] = lrow[r] * corr + psum;
            #pragma unroll
            for (int ds = 0; ds < 4; ++ds) o[ds][r] *= corr;
            int q = lg * 4 + r;
            #pragma unroll
            for (int sub = 0; sub < 4; ++sub)
                Ps[w][q * 72 + sub * 16 + lk] = pb[sub];
        }
        asm volatile("s_waitcnt lgkmcnt(0)" ::: "memory");

        #pragma unroll
        for (int kh = 0; kh < 2; ++kh) {
            bf16x8 pf = *(const bf16x8*)&Ps[w][lk * 72 + kh * 32 + lg * 8];
            #pragma unroll
            for (int ds = 0; ds < 4; ++ds) {
                bf16x8 vf = *(const bf16x8*)&Vt[(ds * 16 + lk) * 72 + kh * 32 + lg * 8];
                o[ds] = __builtin_amdgcn_mfma_f32_16x16x32_bf16(pf, vf, o[ds], 0, 0, 0);
            }
        }
        __syncthreads();
    }

    #pragma unroll
    for (int ds = 0; ds < 4; ++ds)
        #pragma unroll
        for (int r = 0; r < 4; ++r) {
            int q = lg * 4 + r;
            O[(size_t)(b * N + q0 + w * 16 + q) * 1024 + h * 64 + ds * 16 + lk] =
                f2bf(o[ds][r] / lrow[r]);
        }
}

// ---------------------------------------------------------------------------
// Fused residual + LayerNorm: out = LN(x + gamma*y) * w + b  (+ optional bf16)
// ---------------------------------------------------------------------------
__global__ __launch_bounds__(256) void ln_res_kernel(
    const float* __restrict__ x, const float* __restrict__ y,
    const float* __restrict__ gamma, const float* __restrict__ w,
    const float* __restrict__ bia, float* __restrict__ out,
    unsigned short* __restrict__ out_bf, int C)
{
    const int row = blockIdx.x;
    __shared__ float buf[1024];
    __shared__ float red[8];
    const size_t base = (size_t)row * C;
    float s = 0.f, ss = 0.f;
    for (int c = threadIdx.x; c < C; c += 256) {
        float v = x[base + c] + gamma[c] * y[base + c];
        buf[c] = v; s += v; ss += v * v;
    }
    #pragma unroll
    for (int msk = 1; msk < 64; msk <<= 1) { s += __shfl_xor(s, msk); ss += __shfl_xor(ss, msk); }
    int wv = threadIdx.x >> 6, lane = threadIdx.x & 63;
    if (lane == 0) { red[wv * 2] = s; red[wv * 2 + 1] = ss; }
    __syncthreads();
    if (threadIdx.x == 0) {
        float S = 0.f, SS = 0.f;
        #pragma unroll
        for (int i = 0; i < 4; ++i) { S += red[2 * i]; SS += red[2 * i + 1]; }
        red[0] = S; red[1] = SS;
    }
    __syncthreads();
    float mu = red[0] / C;
    float var = red[1] / C - mu * mu;
    float rstd = rsqrtf(var + 1e-5f);
    for (int c = threadIdx.x; c < C; c += 256) {
        float v = (buf[c] - mu) * rstd * w[c] + bia[c];
        out[base + c] = v;
        if (out_bf) out_bf[base + c] = f2bf(v);
    }
}

// ---------------------------------------------------------------------------
extern "C" void kernel_launch(void* const* d_in, const int* in_sizes, int n_in,
                              void* d_out, int out_size, void* d_ws, size_t ws_size,
                              hipStream_t stream)
{
    const float* x      = (const float*)d_in[0];
    const float* demo   = (const float*)d_in[1];
    const float* expl   = (const float*)d_in[2];
    const float* fb     = (const float*)d_in[3];
    const float* w_qkv  = (const float*)d_in[4];
    const float* w_proj = (const float*)d_in[5];
    const float* b_proj = (const float*)d_in[6];
    const float* gamma1 = (const float*)d_in[7];
    const float* gamma2 = (const float*)d_in[8];
    const float* ln1_w  = (const float*)d_in[9];
    const float* ln1_b  = (const float*)d_in[10];
    const float* ln2_w  = (const float*)d_in[11];
    const float* ln2_b  = (const float*)d_in[12];
    const float* w1     = (const float*)d_in[13];
    const float* b1     = (const float*)d_in[14];
    const float* w2     = (const float*)d_in[15];
    const float* b2     = (const float*)d_in[16];
    float* out = (float*)d_out;

    const int B = 8, N = 1024, C = 1024, F = 4096, H = 16;
    const int M = B * N;                        // 8192
    const size_t Mi = 1048576;

    float* ws = (float*)d_ws;
    unsigned short* QKbf = (unsigned short*)ws;              // M x 2048 bf16
    unsigned short* Obf  = (unsigned short*)ws;              // M x 1024 bf16
    float*          H2   = ws;                               // M x 1024 f32
    unsigned short* Qbf  = (unsigned short*)(ws + 8 * Mi);   // M x 1024 bf16
    unsigned short* Kbf  = (unsigned short*)(ws + 12 * Mi);
    unsigned short* Vbf  = (unsigned short*)(ws + 16 * Mi);
    unsigned short* Hid  = (unsigned short*)(ws + 8 * Mi);   // M x 4096 bf16
    unsigned short* Ebf  = (unsigned short*)(ws + 24 * Mi);
    unsigned short* Xbf  = (unsigned short*)(ws + 28 * Mi);
    float*          Pb   = ws + 24 * Mi;                     // M x 1024 f32
    float*          X1   = ws + 32 * Mi;                     // M x 1024 f32
    unsigned short* X1bf = (unsigned short*)(ws + 40 * Mi);
    unsigned short* Wt   = (unsigned short*)(ws + 44 * Mi);
    unsigned short* wqkvT  = Wt;                             // [3072][1024]
    unsigned short* wprojT = Wt + (size_t)3145728;           // [1024][1024]
    unsigned short* w1T    = wprojT + (size_t)1048576;       // [4096][1024]
    unsigned short* w2T    = w1T + (size_t)4194304;          // [1024][4096]

    dim3 blk(256);
    dim3 blk5(512);
    const int MC = M * C;

    hipLaunchKernelGGL(cvt_bf16, dim3(MC / 1024), blk, 0, stream, expl, Ebf, MC);
    hipLaunchKernelGGL(cvt_bf16, dim3(MC / 1024), blk, 0, stream, x, Xbf, MC);
    hipLaunchKernelGGL(transpose_cvt, dim3(96, 32), blk, 0, stream, w_qkv, wqkvT, C, 3 * C);
    hipLaunchKernelGGL(transpose_cvt, dim3(32, 32), blk, 0, stream, w_proj, wprojT, C, C);
    hipLaunchKernelGGL(transpose_cvt, dim3(128, 32), blk, 0, stream, w1, w1T, C, F);
    hipLaunchKernelGGL(transpose_cvt, dim3(32, 128), blk, 0, stream, w2, w2T, F, C);

    // QK projection (explanation) -> bf16; V projection (x) -> bf16
    hipLaunchKernelGGL((gemm2<0,1,256>), dim3(256), blk5, 0, stream, Ebf, wqkvT, (const float*)nullptr, (void*)QKbf, M, 2048, C, 2048);
    hipLaunchKernelGGL((gemm2<0,1,128>), dim3(256), blk5, 0, stream, Xbf, wqkvT + (size_t)2048 * 1024, (const float*)nullptr, (void*)Vbf, M, 1024, C, 1024);

    // drofe: bf16 QK -> rotated bf16 Q (scaled), K
    hipLaunchKernelGGL(drofe_bf, dim3(M * 512 / 256), blk, 0, stream, QKbf, Qbf, Kbf, fb, demo, N);

    // attention -> bf16 O
    hipLaunchKernelGGL(attn_mfma, dim3(B * H * (N / 64)), blk, 0, stream, Qbf, Kbf, Vbf, Obf, B, H, N);

    // output projection
    hipLaunchKernelGGL((gemm2<1,0,128>), dim3(256), blk5, 0, stream, Obf, wprojT, b_proj, (void*)Pb, M, 1024, C, 1024);

    // residual + LN1 (f32 + bf16)
    hipLaunchKernelGGL(ln_res_kernel, dim3(M), blk, 0, stream, x, Pb, gamma1, ln1_w, ln1_b, X1, X1bf, C);

    // MLP
    hipLaunchKernelGGL((gemm2<2,1,256>), dim3(512), blk5, 0, stream, X1bf, w1T, b1, (void*)Hid, M, F, C, F);
    hipLaunchKernelGGL((gemm2<1,0,128>), dim3(256), blk5, 0, stream, Hid, w2T, b2, (void*)H2, M, 1024, F, 1024);

    // residual + LN2 -> out
    hipLaunchKernelGGL(ln_res_kernel, dim3(M), blk, 0, stream, X1, H2, gamma2, ln2_w, ln2_b, out, (unsigned short*)nullptr, C);
}